// Round 4
// baseline (162.601 us; speedup 1.0000x reference)
//
#include <hip/hip_runtime.h>

// Fused LSTM-heads + 4-layer MLP. Weights pre-packed (h2 pairs, bias folded)
// into __device__ globals by a prep kernel; main kernel reads them at
// wave-uniform compile-time offsets -> compiler selects s_load (scalar pipe,
// K$), freeing the LDS unit entirely. Activations stay per-lane in VGPRs,
// math via v_dot2_f32_f16. One thread = 2 rows, fully unrolled.

#define KSEQ 11
#define CIN  34
#define CMID 51
#define POUT 5
#define BLK  256
#define RPT  2

#define P1     18   // pairs for L1/L4 inputs: 17 data pairs + {bias, 0}
#define P1PAD  24   // row stride in u32 (96B, 32B-aligned)
#define P2     26   // pairs for L2/L3 inputs: 25 data pairs + {z[50], bias}
#define P2PAD  32   // row stride in u32 (128B, 32B-aligned)

typedef _Float16 h2 __attribute__((ext_vector_type(2)));

// ---- packed weight storage (written by prep kernel each launch) ----
__device__ __align__(16) float    g_lstm[KSEQ * 24];        // per k: Wih[16] + Bg[8]
__device__ __align__(16) unsigned g_w1[CMID * P1PAD];
__device__ __align__(16) unsigned g_w2[CMID * P2PAD];
__device__ __align__(16) unsigned g_w3[CIN  * P2PAD];
__device__ __align__(16) unsigned g_w4[POUT * P1PAD];

__device__ __forceinline__ h2 pk(float a, float b) {
    auto r = __builtin_amdgcn_cvt_pkrtz(a, b);
    union { decltype(r) f; h2 h; } c; c.f = r; return c.h;
}
__device__ __forceinline__ h2 as_h2(unsigned u) {
    union { unsigned u; h2 h; } c; c.u = u; return c.h;
}
__device__ __forceinline__ unsigned as_u32(h2 h) {
    union { h2 h; unsigned u; } c; c.h = h; return c.u;
}
__device__ __forceinline__ float fdot2f(h2 a, h2 b, float c) {
#if __has_builtin(__builtin_amdgcn_fdot2)
    return __builtin_amdgcn_fdot2(a, b, c, false);
#else
    return (float)a.x * (float)b.x + (float)a.y * (float)b.y + c;
#endif
}
__device__ __forceinline__ float fast_exp(float x) {
#if __has_builtin(__builtin_amdgcn_exp2f)
    return __builtin_amdgcn_exp2f(x * 1.44269504088896340736f);
#else
    return __expf(x);
#endif
}
__device__ __forceinline__ float fast_rcp(float x) {
#if __has_builtin(__builtin_amdgcn_rcpf)
    return __builtin_amdgcn_rcpf(x);
#else
    return 1.0f / x;
#endif
}
__device__ __forceinline__ float sig1(float x)  { return fast_rcp(1.0f + fast_exp(-x)); }
__device__ __forceinline__ float tanh1(float x) {
    float e = fast_exp(2.0f * x);
    return 1.0f - 2.0f * fast_rcp(e + 1.0f);
}

// ---- prep: pack weights into consumption layout (grid-stride, 8x256) ----
__global__ void prep_weights(const float* __restrict__ W_ih, const float* __restrict__ b_ih,
                             const float* __restrict__ b_hh,
                             const float* __restrict__ W1, const float* __restrict__ b1,
                             const float* __restrict__ W2, const float* __restrict__ b2,
                             const float* __restrict__ W3, const float* __restrict__ b3,
                             const float* __restrict__ W4, const float* __restrict__ b4)
{
    const int gid = blockIdx.x * blockDim.x + threadIdx.x;
    const int gs  = gridDim.x * blockDim.x;

    for (int i = gid; i < KSEQ * 24; i += gs) {
        int k = i / 24, c = i - k * 24;
        float v;
        if (c < 16)      v = W_ih[k * 16 + c];
        else             v = b_ih[k * 8 + (c - 16)] + b_hh[k * 8 + (c - 16)];
        g_lstm[i] = v;
    }
    for (int i = gid; i < CMID * P1PAD; i += gs) {
        int n = i / P1PAD, c = i - n * P1PAD;
        float a = 0.0f, b = 0.0f;
        if (c < 17)       { a = W1[n * CIN + 2 * c]; b = W1[n * CIN + 2 * c + 1]; }
        else if (c == 17) { a = b1[n]; }
        g_w1[i] = as_u32(pk(a, b));
    }
    for (int i = gid; i < CMID * P2PAD; i += gs) {
        int n = i / P2PAD, c = i - n * P2PAD;
        float a = 0.0f, b = 0.0f;
        if (c < 25)       { a = W2[n * CMID + 2 * c]; b = W2[n * CMID + 2 * c + 1]; }
        else if (c == 25) { a = W2[n * CMID + 50]; b = b2[n]; }
        g_w2[i] = as_u32(pk(a, b));
    }
    for (int i = gid; i < CIN * P2PAD; i += gs) {
        int m = i / P2PAD, c = i - m * P2PAD;
        float a = 0.0f, b = 0.0f;
        if (c < 25)       { a = W3[m * CMID + 2 * c]; b = W3[m * CMID + 2 * c + 1]; }
        else if (c == 25) { a = W3[m * CMID + 50]; b = b3[m]; }
        g_w3[i] = as_u32(pk(a, b));
    }
    for (int i = gid; i < POUT * P1PAD; i += gs) {
        int p = i / P1PAD, c = i - p * P1PAD;
        float a = 0.0f, b = 0.0f;
        if (c < 17)       { a = W4[p * CIN + 2 * c]; b = W4[p * CIN + 2 * c + 1]; }
        else if (c == 17) { a = b4[p]; }
        g_w4[i] = as_u32(pk(a, b));
    }
}

// Dot of two activation-pair arrays (2 rows) against one uniform weight row.
template<int NP, int NW4>
__device__ __forceinline__ void dot2x(const unsigned* __restrict__ wrow,
                                      const h2* a, const h2* b,
                                      float& r0, float& r1)
{
    const uint4* w4 = reinterpret_cast<const uint4*>(wrow);
    float s0 = 0.0f, s1 = 0.0f;
    #pragma unroll
    for (int q = 0; q < NW4; ++q) {
        uint4 w = w4[q];
        if (4 * q + 0 < NP) { h2 h = as_h2(w.x); s0 = fdot2f(a[4*q+0], h, s0); s1 = fdot2f(b[4*q+0], h, s1); }
        if (4 * q + 1 < NP) { h2 h = as_h2(w.y); s0 = fdot2f(a[4*q+1], h, s0); s1 = fdot2f(b[4*q+1], h, s1); }
        if (4 * q + 2 < NP) { h2 h = as_h2(w.z); s0 = fdot2f(a[4*q+2], h, s0); s1 = fdot2f(b[4*q+2], h, s1); }
        if (4 * q + 3 < NP) { h2 h = as_h2(w.w); s0 = fdot2f(a[4*q+3], h, s0); s1 = fdot2f(b[4*q+3], h, s1); }
    }
    r0 = s0; r1 = s1;
}

__global__ __launch_bounds__(BLK, 4)
void fused_rnn_mlp(const float* __restrict__ input, float* __restrict__ out, int nrows)
{
    const int tid = threadIdx.x;
    const long long row0 = ((long long)blockIdx.x * BLK + tid) * RPT;
    if (row0 + RPT > nrows) return;

    // ---- load 2 rows (8B-aligned: 34*4 = 136B stride) ----
    float2 xa[17], xb[17];
    {
        const float2* pa = reinterpret_cast<const float2*>(input + row0 * CIN);
        const float2* pb = reinterpret_cast<const float2*>(input + (row0 + 1) * CIN);
        #pragma unroll
        for (int j = 0; j < 17; ++j) { xa[j] = pa[j]; xb[j] = pb[j]; }
    }

    // ---- LSTM heads (fp32, params via uniform scalar loads) ----
    h2 ca[P1], cb[P1];
    #pragma unroll
    for (int k = 0; k < KSEQ; ++k) {
        const float4* wk = reinterpret_cast<const float4*>(&g_lstm[k * 24]);
        float4 WA = wk[0];  // gate i rows (g0,g1)
        float4 WC = wk[2];  // gate g rows (g4,g5)
        float4 WD = wk[3];  // gate o rows (g6,g7)
        float4 B0 = wk[4];  // Bg[0..3]
        float4 B1 = wk[5];  // Bg[4..7]
        {
            float x0 = xa[k].x, x1 = xa[k].y;
            float gi0 = B0.x + x0 * WA.x + x1 * WA.y;
            float gi1 = B0.y + x0 * WA.z + x1 * WA.w;
            float gg0 = B1.x + x0 * WC.x + x1 * WC.y;
            float gg1 = B1.y + x0 * WC.z + x1 * WC.w;
            float go0 = B1.z + x0 * WD.x + x1 * WD.y;
            float go1 = B1.w + x0 * WD.z + x1 * WD.w;
            float c0 = sig1(gi0) * tanh1(gg0);
            float c1 = sig1(gi1) * tanh1(gg1);
            ca[k] = pk(sig1(go0) * tanh1(c0), sig1(go1) * tanh1(c1));
        }
        {
            float x0 = xb[k].x, x1 = xb[k].y;
            float gi0 = B0.x + x0 * WA.x + x1 * WA.y;
            float gi1 = B0.y + x0 * WA.z + x1 * WA.w;
            float gg0 = B1.x + x0 * WC.x + x1 * WC.y;
            float gg1 = B1.y + x0 * WC.z + x1 * WC.w;
            float go0 = B1.z + x0 * WD.x + x1 * WD.y;
            float go1 = B1.w + x0 * WD.z + x1 * WD.w;
            float c0 = sig1(gi0) * tanh1(gg0);
            float c1 = sig1(gi1) * tanh1(gg1);
            cb[k] = pk(sig1(go0) * tanh1(c0), sig1(go1) * tanh1(c1));
        }
    }
    #pragma unroll
    for (int t = 0; t < 6; ++t) {       // passthrough x[22..33] -> pairs 11..16
        ca[11 + t] = pk(xa[11 + t].x, xa[11 + t].y);
        cb[11 + t] = pk(xb[11 + t].x, xb[11 + t].y);
    }
    ca[17] = pk(1.0f, 0.0f);
    cb[17] = pk(1.0f, 0.0f);

    // ---- L1 -> f16 pairs ----
    h2 za[P2], zb[P2];
    #pragma unroll
    for (int n = 0; n < 50; n += 2) {
        float a0, a1, b0, b1v;
        dot2x<P1, P1PAD / 4>(&g_w1[n * P1PAD],       ca, cb, a0, b0);
        dot2x<P1, P1PAD / 4>(&g_w1[(n + 1) * P1PAD], ca, cb, a1, b1v);
        za[n / 2] = pk(fmaxf(a0, 0.0f), fmaxf(a1, 0.0f));
        zb[n / 2] = pk(fmaxf(b0, 0.0f), fmaxf(b1v, 0.0f));
    }
    {
        float a0, b0;
        dot2x<P1, P1PAD / 4>(&g_w1[50 * P1PAD], ca, cb, a0, b0);
        za[25] = pk(fmaxf(a0, 0.0f), 1.0f);
        zb[25] = pk(fmaxf(b0, 0.0f), 1.0f);
    }

    // ---- L2 ----
    h2 ya[P2], yb[P2];
    #pragma unroll
    for (int j = 0; j < 50; j += 2) {
        float a0, a1, b0, b1v;
        dot2x<P2, P2PAD / 4>(&g_w2[j * P2PAD],       za, zb, a0, b0);
        dot2x<P2, P2PAD / 4>(&g_w2[(j + 1) * P2PAD], za, zb, a1, b1v);
        ya[j / 2] = pk(fmaxf(a0, 0.0f), fmaxf(a1, 0.0f));
        yb[j / 2] = pk(fmaxf(b0, 0.0f), fmaxf(b1v, 0.0f));
    }
    {
        float a0, b0;
        dot2x<P2, P2PAD / 4>(&g_w2[50 * P2PAD], za, zb, a0, b0);
        ya[25] = pk(fmaxf(a0, 0.0f), 1.0f);
        yb[25] = pk(fmaxf(b0, 0.0f), 1.0f);
    }

    // ---- L3 ----
    h2 ta[P1], tb[P1];
    #pragma unroll
    for (int m = 0; m < CIN; m += 2) {
        float a0, a1, b0, b1v;
        dot2x<P2, P2PAD / 4>(&g_w3[m * P2PAD],       ya, yb, a0, b0);
        dot2x<P2, P2PAD / 4>(&g_w3[(m + 1) * P2PAD], ya, yb, a1, b1v);
        ta[m / 2] = pk(fmaxf(a0, 0.0f), fmaxf(a1, 0.0f));
        tb[m / 2] = pk(fmaxf(b0, 0.0f), fmaxf(b1v, 0.0f));
    }
    ta[17] = pk(1.0f, 0.0f);
    tb[17] = pk(1.0f, 0.0f);

    // ---- L4 + sigmoid + store ----
    float oa[POUT], ob[POUT];
    #pragma unroll
    for (int p = 0; p < POUT; ++p) {
        float a0, b0;
        dot2x<P1, P1PAD / 4>(&g_w4[p * P1PAD], ta, tb, a0, b0);
        oa[p] = sig1(a0);
        ob[p] = sig1(b0);
    }
    float* op0 = out + row0 * POUT;
    float* op1 = out + (row0 + 1) * POUT;
    #pragma unroll
    for (int p = 0; p < POUT; ++p) { op0[p] = oa[p]; op1[p] = ob[p]; }
}

extern "C" void kernel_launch(void* const* d_in, const int* in_sizes, int n_in,
                              void* d_out, int out_size, void* d_ws, size_t ws_size,
                              hipStream_t stream)
{
    const float* input = (const float*)d_in[0];
    const float* W_ih  = (const float*)d_in[1];
    const float* b_ih  = (const float*)d_in[2];
    const float* b_hh  = (const float*)d_in[3];
    const float* W1    = (const float*)d_in[4];
    const float* b1    = (const float*)d_in[5];
    const float* W2    = (const float*)d_in[6];
    const float* b2    = (const float*)d_in[7];
    const float* W3    = (const float*)d_in[8];
    const float* b3    = (const float*)d_in[9];
    const float* W4    = (const float*)d_in[10];
    const float* b4    = (const float*)d_in[11];
    float* out = (float*)d_out;

    int nrows = in_sizes[0] / CIN;
    int grid  = (nrows + BLK * RPT - 1) / (BLK * RPT);

    hipLaunchKernelGGL(prep_weights, dim3(8), dim3(256), 0, stream,
                       W_ih, b_ih, b_hh, W1, b1, W2, b2, W3, b3, W4, b4);
    hipLaunchKernelGGL(fused_rnn_mlp, dim3(grid), dim3(BLK), 0, stream,
                       input, out, nrows);
}

// Round 5
// 141.381 us; speedup vs baseline: 1.1501x; 1.1501x over previous
//
#include <hip/hip_runtime.h>

// Fused LSTM-heads + 4-layer MLP. Weights packed once (prep kernel) into a
// single __device__ buffer in consumption order (f16 pairs, biases folded).
// Main kernel streams weights through the SCALAR pipe via inline-asm
// s_load_dwordx16 (wave-uniform -> SGPRs), feeding v_dot2_f32_f16 with the
// SGPR operand. Zero LDS, zero per-lane weight traffic on VMEM.
// One thread = 2 rows; activations in VGPRs; fully unrolled.

#define KSEQ 11
#define CIN  34
#define CMID 51
#define POUT 5
#define BLK  256
#define RPT  2

#define S1 24                       // u32 stride: rows with 18 used pairs
#define S2 32                       // u32 stride: rows with 26 used pairs
#define OFF_LSTM 0
#define OFF_W1   (12 * S1)          // 288
#define OFF_W2   (OFF_W1 + 51 * S1) // 1512
#define OFF_W3   (OFF_W2 + 51 * S2) // 3144
#define OFF_W4   (OFF_W3 + 34 * S2) // 4232
#define PACK_TOT (OFF_W4 + 5 * S1 + 40)

typedef _Float16 h2  __attribute__((ext_vector_type(2)));
typedef unsigned u16v __attribute__((ext_vector_type(16)));
typedef unsigned u8v  __attribute__((ext_vector_type(8)));

__device__ __align__(256) unsigned g_pack[PACK_TOT];

__device__ __forceinline__ h2 pk(float a, float b) {
    auto r = __builtin_amdgcn_cvt_pkrtz(a, b);
    union { decltype(r) f; h2 h; } c; c.f = r; return c.h;
}
__device__ __forceinline__ h2 as_h2(unsigned u) {
    union { unsigned u; h2 h; } c; c.u = u; return c.h;
}
__device__ __forceinline__ unsigned as_u32(h2 h) {
    union { h2 h; unsigned u; } c; c.h = h; return c.u;
}
__device__ __forceinline__ float uf(unsigned u) {
    union { unsigned u; float f; } c; c.u = u; return c.f;
}
__device__ __forceinline__ float fdot2f(h2 a, h2 b, float c) {
#if __has_builtin(__builtin_amdgcn_fdot2)
    return __builtin_amdgcn_fdot2(a, b, c, false);
#else
    return (float)a.x * (float)b.x + (float)a.y * (float)b.y + c;
#endif
}
__device__ __forceinline__ float fast_exp(float x) {
#if __has_builtin(__builtin_amdgcn_exp2f)
    return __builtin_amdgcn_exp2f(x * 1.44269504088896340736f);
#else
    return __expf(x);
#endif
}
__device__ __forceinline__ float fast_rcp(float x) {
#if __has_builtin(__builtin_amdgcn_rcpf)
    return __builtin_amdgcn_rcpf(x);
#else
    return 1.0f / x;
#endif
}
__device__ __forceinline__ float sig1(float x)  { return fast_rcp(1.0f + fast_exp(-x)); }
__device__ __forceinline__ float tanh1(float x) {
    float e = fast_exp(2.0f * x);
    return 1.0f - 2.0f * fast_rcp(e + 1.0f);
}

// ---- scalar-pipe loads: s_waitcnt fused in-block (rule #18: consumers
// depend on asm OUTPUTS, so they cannot be hoisted above the wait) ----
__device__ __forceinline__ void sload1(const unsigned* p, u16v& c0, u8v& c1) {
    asm volatile("s_load_dwordx16 %0, %2, 0x0\n\t"
                 "s_load_dwordx8  %1, %2, 0x40\n\t"
                 "s_waitcnt lgkmcnt(0)"
                 : "=&s"(c0), "=&s"(c1) : "s"(p));
}
__device__ __forceinline__ void sload2(const unsigned* p, u16v& c0, u16v& c1) {
    asm volatile("s_load_dwordx16 %0, %2, 0x0\n\t"
                 "s_load_dwordx16 %1, %2, 0x40\n\t"
                 "s_waitcnt lgkmcnt(0)"
                 : "=&s"(c0), "=&s"(c1) : "s"(p));
}
__device__ __forceinline__ void sload3(const unsigned* p, u16v& c0, u16v& c1, u16v& c2) {
    asm volatile("s_load_dwordx16 %0, %3, 0x0\n\t"
                 "s_load_dwordx16 %1, %3, 0x40\n\t"
                 "s_load_dwordx16 %2, %3, 0x80\n\t"
                 "s_waitcnt lgkmcnt(0)"
                 : "=&s"(c0), "=&s"(c1), "=&s"(c2) : "s"(p));
}
__device__ __forceinline__ void sload4(const unsigned* p, u16v& c0, u16v& c1, u16v& c2, u16v& c3) {
    asm volatile("s_load_dwordx16 %0, %4, 0x0\n\t"
                 "s_load_dwordx16 %1, %4, 0x40\n\t"
                 "s_load_dwordx16 %2, %4, 0x80\n\t"
                 "s_load_dwordx16 %3, %4, 0xc0\n\t"
                 "s_waitcnt lgkmcnt(0)"
                 : "=&s"(c0), "=&s"(c1), "=&s"(c2), "=&s"(c3) : "s"(p));
}

__device__ __forceinline__ unsigned pick48(const u16v& c0, const u16v& c1, const u16v& c2, int j) {
    return j < 16 ? c0[j] : (j < 32 ? c1[j - 16] : c2[j - 32]);
}
__device__ __forceinline__ unsigned pick24(const u16v& c0, const u8v& c1, int j) {
    return j < 16 ? c0[j] : c1[j - 16];
}

// ---- dot helpers: 2 sample-rows (A,B act arrays) x weight rows ----
__device__ __forceinline__ void dotP1pair(const u16v& c0, const u16v& c1, const u16v& c2,
                                          const h2* A, const h2* B,
                                          float& a0, float& a1, float& b0, float& b1)
{
    float s00 = 0, s01 = 0, s10 = 0, s11 = 0;
    #pragma unroll
    for (int j = 0; j < 18; ++j) {
        h2 w0 = as_h2(pick48(c0, c1, c2, j));
        h2 w1 = as_h2(pick48(c0, c1, c2, j + 24));
        s00 = fdot2f(A[j], w0, s00); s10 = fdot2f(B[j], w0, s10);
        s01 = fdot2f(A[j], w1, s01); s11 = fdot2f(B[j], w1, s11);
    }
    a0 = s00; a1 = s01; b0 = s10; b1 = s11;
}
__device__ __forceinline__ void dotP1one(const u16v& c0, const u8v& c1,
                                         const h2* A, const h2* B, float& a0, float& b0)
{
    float s0 = 0, s1 = 0;
    #pragma unroll
    for (int j = 0; j < 18; ++j) {
        h2 w = as_h2(pick24(c0, c1, j));
        s0 = fdot2f(A[j], w, s0); s1 = fdot2f(B[j], w, s1);
    }
    a0 = s0; b0 = s1;
}
__device__ __forceinline__ void dotP2pair(const u16v& c0, const u16v& c1, const u16v& c2, const u16v& c3,
                                          const h2* A, const h2* B,
                                          float& a0, float& a1, float& b0, float& b1)
{
    float s00 = 0, s01 = 0, s10 = 0, s11 = 0;
    #pragma unroll
    for (int j = 0; j < 26; ++j) {
        h2 w0 = as_h2(j < 16 ? c0[j] : c1[j - 16]);
        h2 w1 = as_h2(j < 16 ? c2[j] : c3[j - 16]);
        s00 = fdot2f(A[j], w0, s00); s10 = fdot2f(B[j], w0, s10);
        s01 = fdot2f(A[j], w1, s01); s11 = fdot2f(B[j], w1, s11);
    }
    a0 = s00; a1 = s01; b0 = s10; b1 = s11;
}
__device__ __forceinline__ void dotP2one(const u16v& c0, const u16v& c1,
                                         const h2* A, const h2* B, float& a0, float& b0)
{
    float s0 = 0, s1 = 0;
    #pragma unroll
    for (int j = 0; j < 26; ++j) {
        h2 w = as_h2(j < 16 ? c0[j] : c1[j - 16]);
        s0 = fdot2f(A[j], w, s0); s1 = fdot2f(B[j], w, s1);
    }
    a0 = s0; b0 = s1;
}

__device__ __forceinline__ void lstm_one(const u16v& c0, const u16v& c1, const u16v& c2, int base,
                                         float2 x, h2& outp)
{
    float w0  = uf(pick48(c0, c1, c2, base + 0)),  w1  = uf(pick48(c0, c1, c2, base + 1));
    float w2  = uf(pick48(c0, c1, c2, base + 2)),  w3  = uf(pick48(c0, c1, c2, base + 3));
    float w8  = uf(pick48(c0, c1, c2, base + 8)),  w9  = uf(pick48(c0, c1, c2, base + 9));
    float w10 = uf(pick48(c0, c1, c2, base + 10)), w11 = uf(pick48(c0, c1, c2, base + 11));
    float w12 = uf(pick48(c0, c1, c2, base + 12)), w13 = uf(pick48(c0, c1, c2, base + 13));
    float w14 = uf(pick48(c0, c1, c2, base + 14)), w15 = uf(pick48(c0, c1, c2, base + 15));
    float B0  = uf(pick48(c0, c1, c2, base + 16)), B1v = uf(pick48(c0, c1, c2, base + 17));
    float B4  = uf(pick48(c0, c1, c2, base + 20)), B5  = uf(pick48(c0, c1, c2, base + 21));
    float B6  = uf(pick48(c0, c1, c2, base + 22)), B7  = uf(pick48(c0, c1, c2, base + 23));

    float x0 = x.x, x1 = x.y;
    float gi0 = B0  + x0 * w0  + x1 * w1;
    float gi1 = B1v + x0 * w2  + x1 * w3;
    float gg0 = B4  + x0 * w8  + x1 * w9;
    float gg1 = B5  + x0 * w10 + x1 * w11;
    float go0 = B6  + x0 * w12 + x1 * w13;
    float go1 = B7  + x0 * w14 + x1 * w15;
    float cc0 = sig1(gi0) * tanh1(gg0);
    float cc1 = sig1(gi1) * tanh1(gg1);
    outp = pk(sig1(go0) * tanh1(cc0), sig1(go1) * tanh1(cc1));
}

// ---- prep: pack weights (f16 pairs, biases folded) into g_pack ----
__global__ void prep_weights(const float* __restrict__ W_ih, const float* __restrict__ b_ih,
                             const float* __restrict__ b_hh,
                             const float* __restrict__ W1, const float* __restrict__ b1,
                             const float* __restrict__ W2, const float* __restrict__ b2,
                             const float* __restrict__ W3, const float* __restrict__ b3,
                             const float* __restrict__ W4, const float* __restrict__ b4)
{
    const int gid = blockIdx.x * blockDim.x + threadIdx.x;
    const int gs  = gridDim.x * blockDim.x;
    for (int i = gid; i < PACK_TOT; i += gs) {
        unsigned v = 0u;
        if (i < OFF_W1) {
            int k = i / S1, c = i - k * S1;
            float f = 0.f;
            if (k < KSEQ) f = (c < 16) ? W_ih[k * 16 + c]
                                       : b_ih[k * 8 + (c - 16)] + b_hh[k * 8 + (c - 16)];
            v = __float_as_uint(f);
        } else if (i < OFF_W2) {
            int r = (i - OFF_W1) / S1, c = (i - OFF_W1) - r * S1;
            float a = 0.f, b = 0.f;
            if (c < 17)       { a = W1[r * CIN + 2 * c]; b = W1[r * CIN + 2 * c + 1]; }
            else if (c == 17) { a = b1[r]; }
            v = as_u32(pk(a, b));
        } else if (i < OFF_W3) {
            int r = (i - OFF_W2) / S2, c = (i - OFF_W2) - r * S2;
            float a = 0.f, b = 0.f;
            if (c < 25)       { a = W2[r * CMID + 2 * c]; b = W2[r * CMID + 2 * c + 1]; }
            else if (c == 25) { a = W2[r * CMID + 50]; b = b2[r]; }
            v = as_u32(pk(a, b));
        } else if (i < OFF_W4) {
            int r = (i - OFF_W3) / S2, c = (i - OFF_W3) - r * S2;
            float a = 0.f, b = 0.f;
            if (c < 25)       { a = W3[r * CMID + 2 * c]; b = W3[r * CMID + 2 * c + 1]; }
            else if (c == 25) { a = W3[r * CMID + 50]; b = b3[r]; }
            v = as_u32(pk(a, b));
        } else if (i < OFF_W4 + 5 * S1) {
            int r = (i - OFF_W4) / S1, c = (i - OFF_W4) - r * S1;
            float a = 0.f, b = 0.f;
            if (c < 17)       { a = W4[r * CIN + 2 * c]; b = W4[r * CIN + 2 * c + 1]; }
            else if (c == 17) { a = b4[r]; }
            v = as_u32(pk(a, b));
        }
        g_pack[i] = v;
    }
}

__global__ __launch_bounds__(BLK, 4)
void fused_rnn_mlp(const float* __restrict__ input, float* __restrict__ out, int nrows)
{
    const int tid = threadIdx.x;
    const long long row0 = ((long long)blockIdx.x * BLK + tid) * RPT;
    if (row0 + RPT > nrows) return;

    // ---- 2 input rows (8B-aligned, 136B stride) ----
    float2 xa[17], xb[17];
    {
        const float2* pa = reinterpret_cast<const float2*>(input + row0 * CIN);
        const float2* pb = reinterpret_cast<const float2*>(input + (row0 + 1) * CIN);
        #pragma unroll
        for (int j = 0; j < 17; ++j) { xa[j] = pa[j]; xb[j] = pb[j]; }
    }

    // ---- LSTM heads -> cat pairs ----
    h2 ca[18], cb[18];
    #pragma unroll
    for (int kp = 0; kp < 6; ++kp) {
        u16v c0, c1, c2;
        sload3(&g_pack[OFF_LSTM + kp * 48], c0, c1, c2);
        lstm_one(c0, c1, c2, 0,  xa[2 * kp], ca[2 * kp]);
        lstm_one(c0, c1, c2, 0,  xb[2 * kp], cb[2 * kp]);
        if (kp < 5) {
            lstm_one(c0, c1, c2, 24, xa[2 * kp + 1], ca[2 * kp + 1]);
            lstm_one(c0, c1, c2, 24, xb[2 * kp + 1], cb[2 * kp + 1]);
        }
    }
    #pragma unroll
    for (int t = 0; t < 6; ++t) {   // passthrough x[22..33] -> pairs 11..16
        ca[11 + t] = pk(xa[11 + t].x, xa[11 + t].y);
        cb[11 + t] = pk(xb[11 + t].x, xb[11 + t].y);
    }
    ca[17] = pk(1.f, 0.f);
    cb[17] = pk(1.f, 0.f);

    // ---- L1 ----
    h2 za[26], zb[26];
    #pragma unroll
    for (int np = 0; np < 25; ++np) {
        u16v c0, c1, c2;
        sload3(&g_pack[OFF_W1 + np * 48], c0, c1, c2);
        float a0, a1, b0v, b1v;
        dotP1pair(c0, c1, c2, ca, cb, a0, a1, b0v, b1v);
        za[np] = pk(fmaxf(a0, 0.f),  fmaxf(a1, 0.f));
        zb[np] = pk(fmaxf(b0v, 0.f), fmaxf(b1v, 0.f));
    }
    {
        u16v c0; u8v c1;
        sload1(&g_pack[OFF_W1 + 50 * S1], c0, c1);
        float a0, b0v;
        dotP1one(c0, c1, ca, cb, a0, b0v);
        za[25] = pk(fmaxf(a0, 0.f), 1.f);
        zb[25] = pk(fmaxf(b0v, 0.f), 1.f);
    }

    // ---- L2 ----
    h2 ya[26], yb[26];
    #pragma unroll
    for (int jp = 0; jp < 25; ++jp) {
        u16v c0, c1, c2, c3;
        sload4(&g_pack[OFF_W2 + jp * 64], c0, c1, c2, c3);
        float a0, a1, b0v, b1v;
        dotP2pair(c0, c1, c2, c3, za, zb, a0, a1, b0v, b1v);
        ya[jp] = pk(fmaxf(a0, 0.f),  fmaxf(a1, 0.f));
        yb[jp] = pk(fmaxf(b0v, 0.f), fmaxf(b1v, 0.f));
    }
    {
        u16v c0, c1;
        sload2(&g_pack[OFF_W2 + 50 * S2], c0, c1);
        float a0, b0v;
        dotP2one(c0, c1, za, zb, a0, b0v);
        ya[25] = pk(fmaxf(a0, 0.f), 1.f);
        yb[25] = pk(fmaxf(b0v, 0.f), 1.f);
    }

    // ---- L3 ----
    h2 ta[18], tb[18];
    #pragma unroll
    for (int mp = 0; mp < 17; ++mp) {
        u16v c0, c1, c2, c3;
        sload4(&g_pack[OFF_W3 + mp * 64], c0, c1, c2, c3);
        float a0, a1, b0v, b1v;
        dotP2pair(c0, c1, c2, c3, ya, yb, a0, a1, b0v, b1v);
        ta[mp] = pk(fmaxf(a0, 0.f),  fmaxf(a1, 0.f));
        tb[mp] = pk(fmaxf(b0v, 0.f), fmaxf(b1v, 0.f));
    }
    ta[17] = pk(1.f, 0.f);
    tb[17] = pk(1.f, 0.f);

    // ---- L4 + sigmoid ----
    float oa[POUT], ob[POUT];
    #pragma unroll
    for (int pp = 0; pp < 2; ++pp) {
        u16v c0, c1, c2;
        sload3(&g_pack[OFF_W4 + pp * 48], c0, c1, c2);
        float a0, a1, b0v, b1v;
        dotP1pair(c0, c1, c2, ta, tb, a0, a1, b0v, b1v);
        oa[2 * pp] = sig1(a0);  oa[2 * pp + 1] = sig1(a1);
        ob[2 * pp] = sig1(b0v); ob[2 * pp + 1] = sig1(b1v);
    }
    {
        u16v c0; u8v c1;
        sload1(&g_pack[OFF_W4 + 4 * S1], c0, c1);
        float a0, b0v;
        dotP1one(c0, c1, ta, tb, a0, b0v);
        oa[4] = sig1(a0); ob[4] = sig1(b0v);
    }

    float* op0 = out + row0 * POUT;
    float* op1 = out + (row0 + 1) * POUT;
    #pragma unroll
    for (int p = 0; p < POUT; ++p) { op0[p] = oa[p]; op1[p] = ob[p]; }
}

extern "C" void kernel_launch(void* const* d_in, const int* in_sizes, int n_in,
                              void* d_out, int out_size, void* d_ws, size_t ws_size,
                              hipStream_t stream)
{
    const float* input = (const float*)d_in[0];
    const float* W_ih  = (const float*)d_in[1];
    const float* b_ih  = (const float*)d_in[2];
    const float* b_hh  = (const float*)d_in[3];
    const float* W1    = (const float*)d_in[4];
    const float* b1    = (const float*)d_in[5];
    const float* W2    = (const float*)d_in[6];
    const float* b2    = (const float*)d_in[7];
    const float* W3    = (const float*)d_in[8];
    const float* b3    = (const float*)d_in[9];
    const float* W4    = (const float*)d_in[10];
    const float* b4    = (const float*)d_in[11];
    float* out = (float*)d_out;

    int nrows = in_sizes[0] / CIN;
    int grid  = (nrows + BLK * RPT - 1) / (BLK * RPT);

    hipLaunchKernelGGL(prep_weights, dim3(8), dim3(256), 0, stream,
                       W_ih, b_ih, b_hh, W1, b1, W2, b2, W3, b3, W4, b4);
    hipLaunchKernelGGL(fused_rnn_mlp, dim3(grid), dim3(BLK), 0, stream,
                       input, out, nrows);
}

// Round 7
// 92.521 us; speedup vs baseline: 1.7574x; 1.5281x over previous
//
#include <hip/hip_runtime.h>

// Fused LSTM-heads + 4-layer MLP on the MATRIX pipe.
// One 64-thread block (1 wave) processes 64 rows:
//   - LSTM: 1 row/lane, weights via inline-asm s_load (scalar pipe)
//   - MLP: v_mfma_f32_16x16x32_f16, 4 M-tiles x N-tiles x 2 K-steps per layer
//   - B-fragments pre-packed in lane order by prep kernel
//   - bias in MFMA C operand; relu+pack via DPP lane^1 pairing
//     (parity-corrected: both lanes of a pair write the IDENTICAL u32)
//   - activations in XOR-swizzled LDS ((row&7)<<2 on u32 index, 16B-safe)
// No barriers (single wave).

#define BLK  64
#define KSEQ 11

typedef _Float16 h2   __attribute__((ext_vector_type(2)));
typedef _Float16 h8   __attribute__((ext_vector_type(8)));
typedef float    f4   __attribute__((ext_vector_type(4)));
typedef unsigned u16v __attribute__((ext_vector_type(16)));

#define N_FRAG_U32 6144   // 24 tiles * 64 lanes * 4 u32 (f16 pairs)
#define N_BIAS     768    // 12 bias-tiles * 64 lanes (f32 bits)
#define N_LSTM     288    // 12 * 24 floats (W_ih 16 + folded bias 8 per k)

__device__ __align__(16) float    g_lstm[N_LSTM];
__device__ __align__(16) unsigned g_frag[N_FRAG_U32];
__device__ __align__(16) unsigned g_bias[N_BIAS];

__device__ __forceinline__ h2 pk(float a, float b) {
    auto r = __builtin_amdgcn_cvt_pkrtz(a, b);
    union { decltype(r) f; h2 h; } c; c.f = r; return c.h;
}
__device__ __forceinline__ unsigned as_u32(h2 h) {
    union { h2 h; unsigned u; } c; c.h = h; return c.u;
}
__device__ __forceinline__ float uf(unsigned u) {
    union { unsigned u; float f; } c; c.u = u; return c.f;
}
__device__ __forceinline__ float fast_exp(float x) {
#if __has_builtin(__builtin_amdgcn_exp2f)
    return __builtin_amdgcn_exp2f(x * 1.44269504088896340736f);
#else
    return __expf(x);
#endif
}
__device__ __forceinline__ float fast_rcp(float x) {
#if __has_builtin(__builtin_amdgcn_rcpf)
    return __builtin_amdgcn_rcpf(x);
#else
    return 1.0f / x;
#endif
}
__device__ __forceinline__ float sig1(float x)  { return fast_rcp(1.0f + fast_exp(-x)); }
__device__ __forceinline__ float tanh1(float x) {
    float e = fast_exp(2.0f * x);
    return 1.0f - 2.0f * fast_rcp(e + 1.0f);
}

// scalar-pipe load of 48 u32 (LSTM params for a k-pair); waitcnt fused in-block
__device__ __forceinline__ void sload3(const unsigned* p, u16v& c0, u16v& c1, u16v& c2) {
    asm volatile("s_load_dwordx16 %0, %3, 0x0\n\t"
                 "s_load_dwordx16 %1, %3, 0x40\n\t"
                 "s_load_dwordx16 %2, %3, 0x80\n\t"
                 "s_waitcnt lgkmcnt(0)"
                 : "=&s"(c0), "=&s"(c1), "=&s"(c2) : "s"(p));
}
__device__ __forceinline__ unsigned pick48(const u16v& c0, const u16v& c1, const u16v& c2, int j) {
    return j < 16 ? c0[j] : (j < 32 ? c1[j - 16] : c2[j - 32]);
}

__device__ __forceinline__ void lstm_one(const u16v& c0, const u16v& c1, const u16v& c2, int base,
                                         float2 x, h2& outp)
{
    float w0  = uf(pick48(c0, c1, c2, base + 0)),  w1  = uf(pick48(c0, c1, c2, base + 1));
    float w2  = uf(pick48(c0, c1, c2, base + 2)),  w3  = uf(pick48(c0, c1, c2, base + 3));
    float w8  = uf(pick48(c0, c1, c2, base + 8)),  w9  = uf(pick48(c0, c1, c2, base + 9));
    float w10 = uf(pick48(c0, c1, c2, base + 10)), w11 = uf(pick48(c0, c1, c2, base + 11));
    float w12 = uf(pick48(c0, c1, c2, base + 12)), w13 = uf(pick48(c0, c1, c2, base + 13));
    float w14 = uf(pick48(c0, c1, c2, base + 14)), w15 = uf(pick48(c0, c1, c2, base + 15));
    float B0  = uf(pick48(c0, c1, c2, base + 16)), B1v = uf(pick48(c0, c1, c2, base + 17));
    float B4  = uf(pick48(c0, c1, c2, base + 20)), B5  = uf(pick48(c0, c1, c2, base + 21));
    float B6  = uf(pick48(c0, c1, c2, base + 22)), B7  = uf(pick48(c0, c1, c2, base + 23));

    float x0 = x.x, x1 = x.y;
    float gi0 = B0  + x0 * w0  + x1 * w1;
    float gi1 = B1v + x0 * w2  + x1 * w3;
    float gg0 = B4  + x0 * w8  + x1 * w9;
    float gg1 = B5  + x0 * w10 + x1 * w11;
    float go0 = B6  + x0 * w12 + x1 * w13;
    float go1 = B7  + x0 * w14 + x1 * w15;
    float cc0 = sig1(gi0) * tanh1(gg0);
    float cc1 = sig1(gi1) * tanh1(gg1);
    outp = pk(sig1(go0) * tanh1(cc0), sig1(go1) * tanh1(cc1));
}

// ---- prep: pack B-fragments, bias tiles, LSTM params ----
// tile ids: L1: 0..7 = ks*4+nt | L2: 8..15 | L3: 16..21 = 16+ks*3+nt | L4: 22..23 = 22+ks
// bias ids: L1: 0..3 | L2: 4..7 | L3: 8..10 | L4: 11
__global__ void prep_weights(const float* __restrict__ W_ih, const float* __restrict__ b_ih,
                             const float* __restrict__ b_hh,
                             const float* __restrict__ W1, const float* __restrict__ b1,
                             const float* __restrict__ W2, const float* __restrict__ b2,
                             const float* __restrict__ W3, const float* __restrict__ b3,
                             const float* __restrict__ W4, const float* __restrict__ b4)
{
    const int gid = blockIdx.x * blockDim.x + threadIdx.x;
    const int gs  = gridDim.x * blockDim.x;

    for (int i = gid; i < N_FRAG_U32; i += gs) {
        int t = i >> 8, rlo = i & 255;
        int lane = rlo >> 2, j = rlo & 3;
        const float* W; int N, K, ld, ks, nt;
        if (t < 8)       { W = W1; N = 51; K = 34; ld = 34; ks = t >> 2;     nt = t & 3; }
        else if (t < 16) { W = W2; N = 51; K = 51; ld = 51; ks = (t-8) >> 2; nt = (t-8) & 3; }
        else if (t < 22) { W = W3; N = 34; K = 51; ld = 51; ks = (t-16) / 3; nt = (t-16) % 3; }
        else             { W = W4; N = 5;  K = 34; ld = 34; ks = t - 22;     nt = 0; }
        int n  = nt * 16 + (lane & 15);
        int k0 = ks * 32 + (lane >> 4) * 8 + 2 * j;
        float a = (n < N && k0     < K) ? W[n * ld + k0]     : 0.f;
        float b = (n < N && k0 + 1 < K) ? W[n * ld + k0 + 1] : 0.f;
        g_frag[i] = as_u32(pk(a, b));
    }
    for (int i = gid; i < N_BIAS; i += gs) {
        int bt = i >> 6, lane = i & 63;
        const float* bv; int N, nt;
        if (bt < 4)       { bv = b1; N = 51; nt = bt; }
        else if (bt < 8)  { bv = b2; N = 51; nt = bt - 4; }
        else if (bt < 11) { bv = b3; N = 34; nt = bt - 8; }
        else              { bv = b4; N = 5;  nt = 0; }
        int col = nt * 16 + (lane & 15);
        g_bias[i] = __float_as_uint(col < N ? bv[col] : 0.f);
    }
    for (int i = gid; i < N_LSTM; i += gs) {
        int k = i / 24, cc = i - k * 24;
        float v = 0.f;
        if (k < KSEQ) v = (cc < 16) ? W_ih[k * 16 + cc]
                                    : b_ih[k * 8 + (cc - 16)] + b_hh[k * 8 + (cc - 16)];
        g_lstm[i] = v;
    }
}

// ---- main kernel helpers ----
__device__ __forceinline__ h8 load_frag(int tile, int l) {
    union { uint4 u; h8 h; } u;
    u.u = *(const uint4*)&g_frag[tile * 256 + l * 4];
    return u.h;
}
__device__ __forceinline__ float dpp_xor1(float x) {   // value from lane^1 (VALU pipe)
    return __int_as_float(__builtin_amdgcn_mov_dpp(__float_as_int(x), 0xB1, 0xF, 0xF, true));
}

__device__ __forceinline__ void read_afrags(h8 (&a)[4][2], const unsigned* act, int l)
{
    const int c = l & 15, g = l >> 4;
    const int mrd = (c & 7) << 2;                        // swizzle mask, row = c
    #pragma unroll
    for (int mt = 0; mt < 4; ++mt)
      #pragma unroll
      for (int ks = 0; ks < 2; ++ks) {
        int idx = (mt * 16 + c) * 32 + ((ks * 16 + g * 4) ^ mrd);
        union { uint4 u; h8 h; } u;
        u.u = *(const uint4*)&act[idx];
        a[mt][ks] = u.h;
      }
}

template<int NT, int TBASE, int BBASE>
__device__ __forceinline__ void layer_mfma(const h8 (&a)[4][2], f4 (&acc)[4][4],
                                           const float (&bs)[12], int l)
{
    #pragma unroll
    for (int mt = 0; mt < 4; ++mt)
      #pragma unroll
      for (int nt = 0; nt < NT; ++nt) {
        float b = bs[BBASE + nt];                        // bias rides in C
        acc[mt][nt] = f4{b, b, b, b};
      }
    #pragma unroll
    for (int ks = 0; ks < 2; ++ks)
      #pragma unroll
      for (int nt = 0; nt < NT; ++nt) {
        h8 bf = load_frag(TBASE + ks * NT + nt, l);
        #pragma unroll
        for (int mt = 0; mt < 4; ++mt)
          acc[mt][nt] = __builtin_amdgcn_mfma_f32_16x16x32_f16(a[mt][ks], bf, acc[mt][nt], 0, 0, 0);
      }
}

// relu + f16-pack (DPP lane^1 pairing) + swizzled LDS write.
// PARITY FIX: even lane holds col n (even), odd lane col n+1. Both must write
// the identical u32 (lo = even col, hi = odd col) to the shared address.
template<int NT>
__device__ __forceinline__ void spill_act(const f4 (&acc)[4][4], unsigned* act, int l)
{
    const int g   = l >> 4;
    const int c2  = (l & 15) >> 1;
    const bool odd = (l & 1) != 0;
    #pragma unroll
    for (int mt = 0; mt < 4; ++mt)
      #pragma unroll
      for (int r = 0; r < 4; ++r) {
        const int row = mt * 16 + g * 4 + r;
        const int rowm = ((row & 7) << 2);
        #pragma unroll
        for (int nt = 0; nt < NT; ++nt) {
            float d = fmaxf(acc[mt][nt][r], 0.f);
            float p = dpp_xor1(d);
            float lo = odd ? p : d;
            float hi = odd ? d : p;
            unsigned pr = as_u32(pk(lo, hi));
            act[row * 32 + ((nt * 8 + c2) ^ rowm)] = pr;
        }
      }
}

__global__ __launch_bounds__(BLK, 3)
void fused_rnn_mlp(const float* __restrict__ in, float* __restrict__ out, int nrows)
{
    __shared__ unsigned act[64 * 32];                    // 8 KB, XOR-swizzled pairs
    const int l = threadIdx.x;
    const long long rb = (long long)blockIdx.x * 64;
    if (rb + 64 > nrows) return;

    // bias tiles (12 coalesced dwords, L1-resident)
    float bs[12];
    #pragma unroll
    for (int i = 0; i < 12; ++i) bs[i] = __uint_as_float(g_bias[i * 64 + l]);

    // own row (8B-aligned, 136B stride)
    float2 x[17];
    {
        const float2* rp = (const float2*)(in + (rb + l) * 34);
        #pragma unroll
        for (int i = 0; i < 17; ++i) x[i] = rp[i];
    }

    // LSTM heads (scalar-pipe params) -> 11 h-pairs + 6 passthrough pairs
    unsigned cp[32];
    #pragma unroll
    for (int kp = 0; kp < 6; ++kp) {
        u16v c0, c1, c2;
        sload3((const unsigned*)&g_lstm[kp * 48], c0, c1, c2);
        h2 h;
        lstm_one(c0, c1, c2, 0, x[2 * kp], h);
        cp[2 * kp] = as_u32(h);
        if (kp < 5) {
            lstm_one(c0, c1, c2, 24, x[2 * kp + 1], h);
            cp[2 * kp + 1] = as_u32(h);
        }
    }
    #pragma unroll
    for (int t = 0; t < 6; ++t) cp[11 + t] = as_u32(pk(x[11 + t].x, x[11 + t].y));
    #pragma unroll
    for (int t = 17; t < 32; ++t) cp[t] = 0u;            // zero K-tail (NaN-safe)

    // stage0: write own full row (row = l) swizzled
    {
        const int m = (l & 7) << 2;
        #pragma unroll
        for (int ch = 0; ch < 8; ++ch) {
            uint4 q = make_uint4(cp[4*ch], cp[4*ch+1], cp[4*ch+2], cp[4*ch+3]);
            *(uint4*)&act[l * 32 + ((4 * ch) ^ m)] = q;
        }
    }

    h8 a[4][2];
    f4 acc[4][4];

    read_afrags(a, act, l);
    layer_mfma<4, 0, 0>(a, acc, bs, l);      // L1: 34 -> 51
    spill_act<4>(acc, act, l);

    read_afrags(a, act, l);
    layer_mfma<4, 8, 4>(a, acc, bs, l);      // L2: 51 -> 51
    spill_act<4>(acc, act, l);

    read_afrags(a, act, l);
    layer_mfma<3, 16, 8>(a, acc, bs, l);     // L3: 51 -> 34
    spill_act<3>(acc, act, l);

    read_afrags(a, act, l);
    layer_mfma<1, 22, 11>(a, acc, bs, l);    // L4: 34 -> 5

    // sigmoid + store (D: col = l&15, row = (l>>4)*4 + r  [m89-verified])
    {
        const int c = l & 15, g = l >> 4;
        if (c < 5) {
            #pragma unroll
            for (int mt = 0; mt < 4; ++mt)
              #pragma unroll
              for (int r = 0; r < 4; ++r) {
                float v = sig1(acc[mt][0][r]);
                out[(rb + mt * 16 + g * 4 + r) * 5 + c] = v;
              }
        }
    }
}

extern "C" void kernel_launch(void* const* d_in, const int* in_sizes, int n_in,
                              void* d_out, int out_size, void* d_ws, size_t ws_size,
                              hipStream_t stream)
{
    const float* input = (const float*)d_in[0];
    const float* W_ih  = (const float*)d_in[1];
    const float* b_ih  = (const float*)d_in[2];
    const float* b_hh  = (const float*)d_in[3];
    const float* W1    = (const float*)d_in[4];
    const float* b1    = (const float*)d_in[5];
    const float* W2    = (const float*)d_in[6];
    const float* b2    = (const float*)d_in[7];
    const float* W3    = (const float*)d_in[8];
    const float* b3    = (const float*)d_in[9];
    const float* W4    = (const float*)d_in[10];
    const float* b4    = (const float*)d_in[11];
    float* out = (float*)d_out;

    int nrows = in_sizes[0] / 34;
    int grid  = nrows / BLK;

    hipLaunchKernelGGL(prep_weights, dim3(8), dim3(256), 0, stream,
                       W_ih, b_ih, b_hh, W1, b1, W2, b2, W3, b3, W4, b4);
    hipLaunchKernelGGL(fused_rnn_mlp, dim3(grid), dim3(BLK), 0, stream,
                       input, out, nrows);
}

// Round 8
// 66.713 us; speedup vs baseline: 2.4373x; 1.3869x over previous
//
#include <hip/hip_runtime.h>

// Fused LSTM-heads + 4-layer MLP on the MATRIX pipe.
// 256-thread block = 4 independent wave-slices; each wave owns 64 rows + an
// 8KB LDS activation tile. Spill uses K-PERMUTED pairing (lane-local cols
// c/16+c and 32+c/48+c packed together; next layer's B-fragments pre-packed
// to the same k-order) -> no cross-lane traffic, half the LDS writes.
// Epilogue: sig outputs staged f32 in LDS (9-pad), one barrier, block-wide
// coalesced store of 1280 contiguous floats.

#define BLK  256
#define WPB  4
#define KSEQ 11

typedef _Float16 h2   __attribute__((ext_vector_type(2)));
typedef _Float16 h8   __attribute__((ext_vector_type(8)));
typedef float    f4   __attribute__((ext_vector_type(4)));
typedef unsigned u16v __attribute__((ext_vector_type(16)));

#define N_FRAG_U32 6144   // 24 tiles * 64 lanes * 4 u32 (f16 pairs)
#define N_BIAS     768    // 12 bias-tiles * 64 lanes (f32 bits)
#define N_LSTM     288    // 12 * 24 floats (W_ih 16 + folded bias 8 per k)

__device__ __align__(16) float    g_lstm[N_LSTM];
__device__ __align__(16) unsigned g_frag[N_FRAG_U32];
__device__ __align__(16) unsigned g_bias[N_BIAS];

__device__ __forceinline__ h2 pk(float a, float b) {
    auto r = __builtin_amdgcn_cvt_pkrtz(a, b);
    union { decltype(r) f; h2 h; } c; c.f = r; return c.h;
}
__device__ __forceinline__ unsigned as_u32(h2 h) {
    union { h2 h; unsigned u; } c; c.h = h; return c.u;
}
__device__ __forceinline__ float uf(unsigned u) {
    union { unsigned u; float f; } c; c.u = u; return c.f;
}
__device__ __forceinline__ float fast_exp(float x) {
#if __has_builtin(__builtin_amdgcn_exp2f)
    return __builtin_amdgcn_exp2f(x * 1.44269504088896340736f);
#else
    return __expf(x);
#endif
}
__device__ __forceinline__ float fast_rcp(float x) {
#if __has_builtin(__builtin_amdgcn_rcpf)
    return __builtin_amdgcn_rcpf(x);
#else
    return 1.0f / x;
#endif
}
__device__ __forceinline__ float sig1(float x)  { return fast_rcp(1.0f + fast_exp(-x)); }
__device__ __forceinline__ float tanh1(float x) {
    float e = fast_exp(2.0f * x);
    return 1.0f - 2.0f * fast_rcp(e + 1.0f);
}

// scalar-pipe load of 48 u32 (LSTM params for a k-pair); waitcnt fused in-block
__device__ __forceinline__ void sload3(const unsigned* p, u16v& c0, u16v& c1, u16v& c2) {
    asm volatile("s_load_dwordx16 %0, %3, 0x0\n\t"
                 "s_load_dwordx16 %1, %3, 0x40\n\t"
                 "s_load_dwordx16 %2, %3, 0x80\n\t"
                 "s_waitcnt lgkmcnt(0)"
                 : "=&s"(c0), "=&s"(c1), "=&s"(c2) : "s"(p));
}
__device__ __forceinline__ unsigned pick48(const u16v& c0, const u16v& c1, const u16v& c2, int j) {
    return j < 16 ? c0[j] : (j < 32 ? c1[j - 16] : c2[j - 32]);
}

__device__ __forceinline__ void lstm_one(const u16v& c0, const u16v& c1, const u16v& c2, int base,
                                         float2 x, h2& outp)
{
    float w0  = uf(pick48(c0, c1, c2, base + 0)),  w1  = uf(pick48(c0, c1, c2, base + 1));
    float w2  = uf(pick48(c0, c1, c2, base + 2)),  w3  = uf(pick48(c0, c1, c2, base + 3));
    float w8  = uf(pick48(c0, c1, c2, base + 8)),  w9  = uf(pick48(c0, c1, c2, base + 9));
    float w10 = uf(pick48(c0, c1, c2, base + 10)), w11 = uf(pick48(c0, c1, c2, base + 11));
    float w12 = uf(pick48(c0, c1, c2, base + 12)), w13 = uf(pick48(c0, c1, c2, base + 13));
    float w14 = uf(pick48(c0, c1, c2, base + 14)), w15 = uf(pick48(c0, c1, c2, base + 15));
    float B0  = uf(pick48(c0, c1, c2, base + 16)), B1v = uf(pick48(c0, c1, c2, base + 17));
    float B4  = uf(pick48(c0, c1, c2, base + 20)), B5  = uf(pick48(c0, c1, c2, base + 21));
    float B6  = uf(pick48(c0, c1, c2, base + 22)), B7  = uf(pick48(c0, c1, c2, base + 23));

    float x0 = x.x, x1 = x.y;
    float gi0 = B0  + x0 * w0  + x1 * w1;
    float gi1 = B1v + x0 * w2  + x1 * w3;
    float gg0 = B4  + x0 * w8  + x1 * w9;
    float gg1 = B5  + x0 * w10 + x1 * w11;
    float go0 = B6  + x0 * w12 + x1 * w13;
    float go1 = B7  + x0 * w14 + x1 * w15;
    float cc0 = sig1(gi0) * tanh1(gg0);
    float cc1 = sig1(gi1) * tanh1(gg1);
    outp = pk(sig1(go0) * tanh1(cc0), sig1(go1) * tanh1(cc1));
}

// ---- prep: pack B-fragments, bias tiles, LSTM params ----
// tile ids: L1: 0..7 = ks*4+nt | L2: 8..15 | L3: 16..21 = 16+ks*3+nt | L4: 22..23
// K-pairing: L1 (input from stage0, sequential): (k0, k0+1), k0 = 32ks+8g+2j
//            L2/L3/L4 (input from MFMA spill, permuted): (32ks+4g+j, +16)
__global__ void prep_weights(const float* __restrict__ W_ih, const float* __restrict__ b_ih,
                             const float* __restrict__ b_hh,
                             const float* __restrict__ W1, const float* __restrict__ b1,
                             const float* __restrict__ W2, const float* __restrict__ b2,
                             const float* __restrict__ W3, const float* __restrict__ b3,
                             const float* __restrict__ W4, const float* __restrict__ b4)
{
    const int gid = blockIdx.x * blockDim.x + threadIdx.x;
    const int gs  = gridDim.x * blockDim.x;

    for (int i = gid; i < N_FRAG_U32; i += gs) {
        int t = i >> 8, rlo = i & 255;
        int lane = rlo >> 2, j = rlo & 3;
        const float* W; int N, K, ld, ks, nt;
        if (t < 8)       { W = W1; N = 51; K = 34; ld = 34; ks = t >> 2;     nt = t & 3; }
        else if (t < 16) { W = W2; N = 51; K = 51; ld = 51; ks = (t-8) >> 2; nt = (t-8) & 3; }
        else if (t < 22) { W = W3; N = 34; K = 51; ld = 51; ks = (t-16) / 3; nt = (t-16) % 3; }
        else             { W = W4; N = 5;  K = 34; ld = 34; ks = t - 22;     nt = 0; }
        int n = nt * 16 + (lane & 15);
        int k_lo, k_hi;
        if (t < 8) { k_lo = ks * 32 + (lane >> 4) * 8 + 2 * j; k_hi = k_lo + 1;  }
        else       { k_lo = ks * 32 + (lane >> 4) * 4 + j;     k_hi = k_lo + 16; }
        float a = (n < N && k_lo < K) ? W[n * ld + k_lo] : 0.f;
        float b = (n < N && k_hi < K) ? W[n * ld + k_hi] : 0.f;
        g_frag[i] = as_u32(pk(a, b));
    }
    for (int i = gid; i < N_BIAS; i += gs) {
        int bt = i >> 6, lane = i & 63;
        const float* bv; int N, nt;
        if (bt < 4)       { bv = b1; N = 51; nt = bt; }
        else if (bt < 8)  { bv = b2; N = 51; nt = bt - 4; }
        else if (bt < 11) { bv = b3; N = 34; nt = bt - 8; }
        else              { bv = b4; N = 5;  nt = 0; }
        int col = nt * 16 + (lane & 15);
        g_bias[i] = __float_as_uint(col < N ? bv[col] : 0.f);
    }
    for (int i = gid; i < N_LSTM; i += gs) {
        int k = i / 24, cc = i - k * 24;
        float v = 0.f;
        if (k < KSEQ) v = (cc < 16) ? W_ih[k * 16 + cc]
                                    : b_ih[k * 8 + (cc - 16)] + b_hh[k * 8 + (cc - 16)];
        g_lstm[i] = v;
    }
}

// ---- main kernel helpers ----
__device__ __forceinline__ h8 load_frag(int tile, int l) {
    union { uint4 u; h8 h; } u;
    u.u = *(const uint4*)&g_frag[tile * 256 + l * 4];
    return u.h;
}

__device__ __forceinline__ void read_afrags(h8 (&a)[4][2], const unsigned* my, int l)
{
    const int c = l & 15, g = l >> 4;
    const int mrd = (c & 7) << 2;                        // swizzle mask, row = c
    #pragma unroll
    for (int mt = 0; mt < 4; ++mt)
      #pragma unroll
      for (int ks = 0; ks < 2; ++ks) {
        int idx = (mt * 16 + c) * 32 + ((ks * 16 + g * 4) ^ mrd);
        union { uint4 u; h8 h; } u;
        u.u = *(const uint4*)&my[idx];
        a[mt][ks] = u.h;
      }
}

template<int NT, int TBASE, int BBASE>
__device__ __forceinline__ void layer_mfma(const h8 (&a)[4][2], f4 (&acc)[4][4],
                                           const float (&bs)[12], int l)
{
    #pragma unroll
    for (int mt = 0; mt < 4; ++mt)
      #pragma unroll
      for (int nt = 0; nt < NT; ++nt) {
        float b = bs[BBASE + nt];                        // bias rides in C
        acc[mt][nt] = f4{b, b, b, b};
      }
    #pragma unroll
    for (int ks = 0; ks < 2; ++ks)
      #pragma unroll
      for (int nt = 0; nt < NT; ++nt) {
        h8 bf = load_frag(TBASE + ks * NT + nt, l);
        #pragma unroll
        for (int mt = 0; mt < 4; ++mt)
          acc[mt][nt] = __builtin_amdgcn_mfma_f32_16x16x32_f16(a[mt][ks], bf, acc[mt][nt], 0, 0, 0);
      }
}

// relu + f16-pack, LANE-LOCAL K-permuted pairing:
// u32 at pair-pos q = 16t + c holds cols (32t + c, 32t + 16 + c).
// No DPP, no selects, 2 writes per (mt, r). Bank-balanced under the swizzle.
template<int NT>
__device__ __forceinline__ void spill_act(const f4 (&acc)[4][4], unsigned* my, int l)
{
    const int g = l >> 4, c = l & 15;
    #pragma unroll
    for (int mt = 0; mt < 4; ++mt)
      #pragma unroll
      for (int r = 0; r < 4; ++r) {
        const int row  = mt * 16 + g * 4 + r;
        const int rowm = (row & 7) << 2;
        float d0 = fmaxf(acc[mt][0][r], 0.f);
        float d1 = fmaxf(acc[mt][1][r], 0.f);
        my[row * 32 + (c ^ rowm)] = as_u32(pk(d0, d1));
        float d2 = fmaxf(acc[mt][2][r], 0.f);
        float d3 = (NT >= 4) ? fmaxf(acc[mt][3][r], 0.f) : 0.f;
        my[row * 32 + ((16 + c) ^ rowm)] = as_u32(pk(d2, d3));
      }
}

__global__ __launch_bounds__(BLK, 4)
void fused_rnn_mlp(const float* __restrict__ in, float* __restrict__ out, int nrows)
{
    __shared__ unsigned act[WPB * 2048];                 // 8 KB per wave-slice
    const int tid = threadIdx.x;
    const int w = tid >> 6, l = tid & 63;
    unsigned* my = &act[w * 2048];
    const long long rb = (long long)blockIdx.x * BLK;
    if (rb + BLK > nrows) return;
    const long long rw = rb + w * 64;

    // bias tiles (12 coalesced dwords)
    float bs[12];
    #pragma unroll
    for (int i = 0; i < 12; ++i) bs[i] = uf(g_bias[i * 64 + l]);

    // own row (8B-aligned, 136B stride)
    float2 x[17];
    {
        const float2* rp = (const float2*)(in + (rw + l) * 34);
        #pragma unroll
        for (int i = 0; i < 17; ++i) x[i] = rp[i];
    }

    // LSTM heads (scalar-pipe params) -> 11 h-pairs + 6 passthrough pairs
    unsigned cp[32];
    #pragma unroll
    for (int kp = 0; kp < 6; ++kp) {
        u16v c0, c1, c2;
        sload3((const unsigned*)&g_lstm[kp * 48], c0, c1, c2);
        h2 h;
        lstm_one(c0, c1, c2, 0, x[2 * kp], h);
        cp[2 * kp] = as_u32(h);
        if (kp < 5) {
            lstm_one(c0, c1, c2, 24, x[2 * kp + 1], h);
            cp[2 * kp + 1] = as_u32(h);
        }
    }
    #pragma unroll
    for (int t = 0; t < 6; ++t) cp[11 + t] = as_u32(pk(x[11 + t].x, x[11 + t].y));
    #pragma unroll
    for (int t = 17; t < 32; ++t) cp[t] = 0u;            // zero K-tail (NaN-safe)

    // stage0: write own full row (row = l), sequential pairs, swizzled
    {
        const int m = (l & 7) << 2;
        #pragma unroll
        for (int ch = 0; ch < 8; ++ch) {
            uint4 q = make_uint4(cp[4*ch], cp[4*ch+1], cp[4*ch+2], cp[4*ch+3]);
            *(uint4*)&my[l * 32 + ((4 * ch) ^ m)] = q;
        }
    }

    h8 a[4][2];
    f4 acc[4][4];

    read_afrags(a, my, l);
    layer_mfma<4, 0, 0>(a, acc, bs, l);      // L1: 34 -> 51
    spill_act<4>(acc, my, l);

    read_afrags(a, my, l);
    layer_mfma<4, 8, 4>(a, acc, bs, l);      // L2: 51 -> 51
    spill_act<4>(acc, my, l);

    read_afrags(a, my, l);
    layer_mfma<3, 16, 8>(a, acc, bs, l);     // L3: 51 -> 34
    spill_act<3>(acc, my, l);

    read_afrags(a, my, l);
    layer_mfma<1, 22, 11>(a, acc, bs, l);    // L4: 34 -> 5

    // sigmoid -> stage f32 into own (now dead) act region, 9-padded
    {
        const int c = l & 15, g = l >> 4;
        float* po = (float*)my;
        if (c < 5) {
            #pragma unroll
            for (int mt = 0; mt < 4; ++mt)
              #pragma unroll
              for (int r = 0; r < 4; ++r)
                po[(mt * 16 + g * 4 + r) * 9 + c] = sig1(acc[mt][0][r]);
        }
    }
    __syncthreads();

    // block-wide coalesced store: 1280 contiguous floats
    const long long ob = rb * 5;
    const float* pact = (const float*)act;
    #pragma unroll
    for (int it = 0; it < 5; ++it) {
        int F   = it * 256 + tid;
        int row = (F * 52429) >> 18;                     // F / 5, exact for F < 2^15
        int cc  = F - row * 5;
        out[ob + F] = pact[(row >> 6) * 2048 + (row & 63) * 9 + cc];
    }
}

extern "C" void kernel_launch(void* const* d_in, const int* in_sizes, int n_in,
                              void* d_out, int out_size, void* d_ws, size_t ws_size,
                              hipStream_t stream)
{
    const float* input = (const float*)d_in[0];
    const float* W_ih  = (const float*)d_in[1];
    const float* b_ih  = (const float*)d_in[2];
    const float* b_hh  = (const float*)d_in[3];
    const float* W1    = (const float*)d_in[4];
    const float* b1    = (const float*)d_in[5];
    const float* W2    = (const float*)d_in[6];
    const float* b2    = (const float*)d_in[7];
    const float* W3    = (const float*)d_in[8];
    const float* b3    = (const float*)d_in[9];
    const float* W4    = (const float*)d_in[10];
    const float* b4    = (const float*)d_in[11];
    float* out = (float*)d_out;

    int nrows = in_sizes[0] / 34;
    int grid  = nrows / BLK;

    hipLaunchKernelGGL(prep_weights, dim3(8), dim3(256), 0, stream,
                       W_ih, b_ih, b_hh, W1, b1, W2, b2, W3, b3, W4, b4);
    hipLaunchKernelGGL(fused_rnn_mlp, dim3(grid), dim3(BLK), 0, stream,
                       input, out, nrows);
}